// Round 4
// baseline (673.656 us; speedup 1.0000x reference)
//
#include <hip/hip_runtime.h>

typedef _Float16 f16x8 __attribute__((ext_vector_type(8)));
typedef _Float16 f16x4 __attribute__((ext_vector_type(4)));
typedef float    f32x4 __attribute__((ext_vector_type(4)));

#define SPLIT_SCALE 4096.0f
#define SPLIT_INV   (1.0f / 4096.0f)

// async global->LDS DMA, 16 bytes per lane (dest = wave-uniform base + lane*16)
__device__ __forceinline__ void gld_lds16(const void* g, void* l) {
    __builtin_amdgcn_global_load_lds(
        (const __attribute__((address_space(1))) unsigned int*)g,
        (__attribute__((address_space(3))) unsigned int*)l,
        16, 0, 0);
}

// fp32 -> (hi f16, lo f16 prescaled by 4096). 8 elements/thread. Weights only.
__global__ __launch_bounds__(256) void k_cvt(
    const float* __restrict__ src, _Float16* __restrict__ h, _Float16* __restrict__ l)
{
    const size_t i = ((size_t)blockIdx.x * 256 + threadIdx.x) * 8;
    float4 v0 = *(const float4*)(src + i);
    float4 v1 = *(const float4*)(src + i + 4);
    float vv[8] = {v0.x, v0.y, v0.z, v0.w, v1.x, v1.y, v1.z, v1.w};
    f16x8 hh, ll;
#pragma unroll
    for (int j = 0; j < 8; ++j) {
        _Float16 x = (_Float16)vv[j];
        hh[j] = x;
        ll[j] = (_Float16)((vv[j] - (float)x) * SPLIT_SCALE);
    }
    *(f16x8*)(h + i) = hh;
    *(f16x8*)(l + i) = ll;
}

// ---------------------------------------------------------------------------
// Pipelined split GEMM: C[128x128] = A_f32[M,K] @ (Bh+Bl/4096)[N,K]^T
// A: fp32 global -> VGPR prefetch -> inline hi/lo split -> LDS.
// B: pre-split f16, global_load_lds DMA prefetch. Double-buffered LDS.
// 256 thr = 4 waves (2x2 of 64x64), 16x16x32 f16 MFMA, 3 products.
// ---------------------------------------------------------------------------
__device__ __forceinline__ void gemm_pipe_core(
    const float* __restrict__ Asrc,
    const _Float16* __restrict__ Bsrc_h, const _Float16* __restrict__ Bsrc_l,
    float* __restrict__ C, int K, int m0, int n0)
{
    __shared__ _Float16 AhL[2][128 * 32];
    __shared__ _Float16 AlL[2][128 * 32];
    __shared__ _Float16 BhL[2][128 * 32];
    __shared__ _Float16 BlL[2][128 * 32];

    const int tid  = threadIdx.x;
    const int lane = tid & 63;
    const int wave = tid >> 6;
    const int wm   = (wave >> 1) * 64;
    const int wn   = (wave & 1) * 64;
    const int quad = lane >> 4;
    const int l15  = lane & 15;

    // ---- A staging: thread -> row tid>>1, cols (tid&1)*16 .. +15 (fp32) ----
    const int arow = tid >> 1;
    const int acol = (tid & 1) * 16;
    const float* Ap = Asrc + (size_t)(m0 + arow) * (size_t)K + acol;
    const int aoff = arow * 32 + acol;          // LDS elem offset

    // ---- B staging: DMA, wave covers rows wave*32..+32 ----
    const int r0 = wave * 32 + (lane >> 2);
    const int kc = (lane & 3) * 8;
    const size_t gB0 = (size_t)(n0 + r0) * (size_t)K + kc;
    const size_t gB1 = gB0 + (size_t)16 * K;
    const int l0 = (wave * 32) * 32;
    const int l1 = l0 + 16 * 32;

    f32x4 accm[4][4], accc[4][4];
#pragma unroll
    for (int i = 0; i < 4; ++i)
#pragma unroll
        for (int j = 0; j < 4; ++j) {
            accm[i][j] = (f32x4){0.f, 0.f, 0.f, 0.f};
            accc[i][j] = (f32x4){0.f, 0.f, 0.f, 0.f};
        }

    const int nIter = K >> 5;

    // ---- prologue: stage tile 0 into buffer 0 ----
    {
        float4 a0 = *(const float4*)(Ap);
        float4 a1 = *(const float4*)(Ap + 4);
        float4 a2 = *(const float4*)(Ap + 8);
        float4 a3 = *(const float4*)(Ap + 12);
        gld_lds16(Bsrc_h + gB0, BhL[0] + l0);
        gld_lds16(Bsrc_h + gB1, BhL[0] + l1);
        gld_lds16(Bsrc_l + gB0, BlL[0] + l0);
        gld_lds16(Bsrc_l + gB1, BlL[0] + l1);
        float vv[16] = {a0.x, a0.y, a0.z, a0.w, a1.x, a1.y, a1.z, a1.w,
                        a2.x, a2.y, a2.z, a2.w, a3.x, a3.y, a3.z, a3.w};
        f16x8 h0, h1, lo0, lo1;
#pragma unroll
        for (int j = 0; j < 8; ++j) {
            _Float16 x = (_Float16)vv[j];
            h0[j]  = x;
            lo0[j] = (_Float16)((vv[j] - (float)x) * SPLIT_SCALE);
            x = (_Float16)vv[j + 8];
            h1[j]  = x;
            lo1[j] = (_Float16)((vv[j + 8] - (float)x) * SPLIT_SCALE);
        }
        *(f16x8*)&AhL[0][aoff]     = h0;
        *(f16x8*)&AhL[0][aoff + 8] = h1;
        *(f16x8*)&AlL[0][aoff]     = lo0;
        *(f16x8*)&AlL[0][aoff + 8] = lo1;
    }

    for (int it = 0; it < nIter; ++it) {
        __syncthreads();   // buffer[it&1] fully staged (ds_writes + own DMA drained)

        const int cur = it & 1;
        const int nxt = cur ^ 1;
        const bool more = (it + 1) < nIter;

        // ---- issue prefetch for tile it+1 (no waits here) ----
        float4 a0, a1, a2, a3;
        if (more) {
            const float* Apn = Ap + (size_t)(it + 1) * 32;
            a0 = *(const float4*)(Apn);
            a1 = *(const float4*)(Apn + 4);
            a2 = *(const float4*)(Apn + 8);
            a3 = *(const float4*)(Apn + 12);
            const size_t kb = (size_t)(it + 1) * 32;
            gld_lds16(Bsrc_h + gB0 + kb, BhL[nxt] + l0);
            gld_lds16(Bsrc_h + gB1 + kb, BhL[nxt] + l1);
            gld_lds16(Bsrc_l + gB0 + kb, BlL[nxt] + l0);
            gld_lds16(Bsrc_l + gB1 + kb, BlL[nxt] + l1);
        }

        // ---- consume current buffer ----
        const _Float16* Ahc = AhL[cur];
        const _Float16* Alc = AlL[cur];
        const _Float16* Bhc = BhL[cur];
        const _Float16* Blc = BlL[cur];

        f16x8 fah[4], fal[4], fbh[4], fbl[4];
#pragma unroll
        for (int i = 0; i < 4; ++i) {
            fah[i] = *(const f16x8*)&Ahc[(wm + i * 16 + l15) * 32 + quad * 8];
            fal[i] = *(const f16x8*)&Alc[(wm + i * 16 + l15) * 32 + quad * 8];
            fbh[i] = *(const f16x8*)&Bhc[(wn + i * 16 + l15) * 32 + quad * 8];
            fbl[i] = *(const f16x8*)&Blc[(wn + i * 16 + l15) * 32 + quad * 8];
        }
#pragma unroll
        for (int i = 0; i < 4; ++i)
#pragma unroll
            for (int j = 0; j < 4; ++j) {
                accm[i][j] = __builtin_amdgcn_mfma_f32_16x16x32_f16(fah[i], fbh[j], accm[i][j], 0, 0, 0);
                accc[i][j] = __builtin_amdgcn_mfma_f32_16x16x32_f16(fah[i], fbl[j], accc[i][j], 0, 0, 0);
                accc[i][j] = __builtin_amdgcn_mfma_f32_16x16x32_f16(fal[i], fbh[j], accc[i][j], 0, 0, 0);
            }

        // keep the A-convert (and its vmcnt wait) BELOW the MFMA block
        __builtin_amdgcn_sched_barrier(0);

        if (more) {
            float vv[16] = {a0.x, a0.y, a0.z, a0.w, a1.x, a1.y, a1.z, a1.w,
                            a2.x, a2.y, a2.z, a2.w, a3.x, a3.y, a3.z, a3.w};
            f16x8 h0, h1, lo0, lo1;
#pragma unroll
            for (int j = 0; j < 8; ++j) {
                _Float16 x = (_Float16)vv[j];
                h0[j]  = x;
                lo0[j] = (_Float16)((vv[j] - (float)x) * SPLIT_SCALE);
                x = (_Float16)vv[j + 8];
                h1[j]  = x;
                lo1[j] = (_Float16)((vv[j + 8] - (float)x) * SPLIT_SCALE);
            }
            *(f16x8*)&AhL[nxt][aoff]     = h0;
            *(f16x8*)&AhL[nxt][aoff + 8] = h1;
            *(f16x8*)&AlL[nxt][aoff]     = lo0;
            *(f16x8*)&AlL[nxt][aoff + 8] = lo1;
        }
    }

    // ---- epilogue: D[m = quad*4 + r][n = lane&15] ----
#pragma unroll
    for (int i = 0; i < 4; ++i)
#pragma unroll
        for (int j = 0; j < 4; ++j)
#pragma unroll
            for (int r = 0; r < 4; ++r) {
                const int row = m0 + wm + i * 16 + quad * 4 + r;
                const int col = n0 + wn + j * 16 + l15;
                C[(size_t)row * 512 + col] = accm[i][j][r] + accc[i][j][r] * SPLIT_INV;
            }
}

// blocks [0,512): Apical = TE @ Wa^T ; [512,528): Basal = SE @ Wb^T
__global__ __launch_bounds__(256, 2) void k_front(
    const float* __restrict__ TE, const float* __restrict__ SE,
    const _Float16* __restrict__ Wah, const _Float16* __restrict__ Wal,
    const _Float16* __restrict__ Wbh, const _Float16* __restrict__ Wbl,
    float* __restrict__ Abuf, float* __restrict__ Cb)
{
    const int bid = blockIdx.x;
    if (bid < 512) {
        gemm_pipe_core(TE, Wah, Wal, Abuf, 3136, (bid >> 2) * 128, (bid & 3) * 128);
    } else {
        const int b = bid - 512;
        gemm_pipe_core(SE, Wbh, Wbl, Cb, 3136, (b >> 2) * 128, (b & 3) * 128);
    }
}

// H = SP(f16 exact) @ (W1h + W1l/4096)^T ; DMA-prefetch double buffer.
__global__ __launch_bounds__(256, 2) void k_gemm3(
    const _Float16* __restrict__ SPh, const _Float16* __restrict__ W1h,
    const _Float16* __restrict__ W1l, float* __restrict__ H)
{
    __shared__ _Float16 AsL[2][128 * 32];
    __shared__ _Float16 BhsL[2][128 * 32];
    __shared__ _Float16 BlsL[2][128 * 32];

    const int bid = blockIdx.x;
    const int m0 = (bid >> 2) * 128, n0 = (bid & 3) * 128;
    const int tid  = threadIdx.x;
    const int lane = tid & 63;
    const int wave = tid >> 6;
    const int wm   = (wave >> 1) * 64;
    const int wn   = (wave & 1) * 64;
    const int quad = lane >> 4;
    const int l15  = lane & 15;

    const int r0 = wave * 32 + (lane >> 2);
    const int kc = (lane & 3) * 8;
    const size_t gA0 = (size_t)(m0 + r0) * 512 + kc;
    const size_t gA1 = gA0 + (size_t)16 * 512;
    const size_t gB0 = (size_t)(n0 + r0) * 512 + kc;
    const size_t gB1 = gB0 + (size_t)16 * 512;
    const int l0 = (wave * 32) * 32;
    const int l1 = l0 + 16 * 32;

    f32x4 accm[4][4], accl[4][4];
#pragma unroll
    for (int i = 0; i < 4; ++i)
#pragma unroll
        for (int j = 0; j < 4; ++j) {
            accm[i][j] = (f32x4){0.f, 0.f, 0.f, 0.f};
            accl[i][j] = (f32x4){0.f, 0.f, 0.f, 0.f};
        }

    // prologue: tile 0 -> buffer 0
    gld_lds16(SPh + gA0, AsL[0] + l0);
    gld_lds16(SPh + gA1, AsL[0] + l1);
    gld_lds16(W1h + gB0, BhsL[0] + l0);
    gld_lds16(W1h + gB1, BhsL[0] + l1);
    gld_lds16(W1l + gB0, BlsL[0] + l0);
    gld_lds16(W1l + gB1, BlsL[0] + l1);

    for (int it = 0; it < 16; ++it) {
        __syncthreads();
        const int cur = it & 1;
        const int nxt = cur ^ 1;
        if (it + 1 < 16) {
            const size_t kb = (size_t)(it + 1) * 32;
            gld_lds16(SPh + gA0 + kb, AsL[nxt] + l0);
            gld_lds16(SPh + gA1 + kb, AsL[nxt] + l1);
            gld_lds16(W1h + gB0 + kb, BhsL[nxt] + l0);
            gld_lds16(W1h + gB1 + kb, BhsL[nxt] + l1);
            gld_lds16(W1l + gB0 + kb, BlsL[nxt] + l0);
            gld_lds16(W1l + gB1 + kb, BlsL[nxt] + l1);
        }

        const _Float16* Asc = AsL[cur];
        const _Float16* Bhc = BhsL[cur];
        const _Float16* Blc = BlsL[cur];
        f16x8 fa[4], fbh[4], fbl[4];
#pragma unroll
        for (int i = 0; i < 4; ++i) {
            fa[i]  = *(const f16x8*)&Asc[(wm + i * 16 + l15) * 32 + quad * 8];
            fbh[i] = *(const f16x8*)&Bhc[(wn + i * 16 + l15) * 32 + quad * 8];
            fbl[i] = *(const f16x8*)&Blc[(wn + i * 16 + l15) * 32 + quad * 8];
        }
#pragma unroll
        for (int i = 0; i < 4; ++i)
#pragma unroll
            for (int j = 0; j < 4; ++j) {
                accm[i][j] = __builtin_amdgcn_mfma_f32_16x16x32_f16(fa[i], fbh[j], accm[i][j], 0, 0, 0);
                accl[i][j] = __builtin_amdgcn_mfma_f32_16x16x32_f16(fa[i], fbl[j], accl[i][j], 0, 0, 0);
            }
    }

#pragma unroll
    for (int i = 0; i < 4; ++i)
#pragma unroll
        for (int j = 0; j < 4; ++j)
#pragma unroll
            for (int r = 0; r < 4; ++r) {
                const int row = m0 + wm + i * 16 + quad * 4 + r;
                const int col = n0 + wn + j * 16 + l15;
                H[(size_t)row * 512 + col] = accm[i][j][r] + accl[i][j][r] * SPLIT_INV;
            }
}

// mb/ma/ms scan over T=8; emits SP (f16, exact 0/1).
__global__ __launch_bounds__(256) void k_scan1(
    const float* __restrict__ Abuf, const float* __restrict__ Cb,
    _Float16* __restrict__ SPh)
{
    const int idx = blockIdx.x * 256 + threadIdx.x;
    const int r = idx >> 7;
    const int f = (idx & 127) << 2;
    const int b = r >> 5;

    float mb[4] = {0, 0, 0, 0}, ma[4] = {0, 0, 0, 0}, ms[4] = {0, 0, 0, 0};
#pragma unroll
    for (int t = 0; t < 8; ++t) {
        float4 av = *(const float4*)(Abuf + ((size_t)(t * 2048 + r) << 9) + f);
        float4 bv = *(const float4*)(Cb + ((size_t)(t * 64 + b) << 9) + f);
        float a[4] = {av.x, av.y, av.z, av.w};
        float ba[4] = {bv.x, bv.y, bv.z, bv.w};
        f16x4 sp;
#pragma unroll
        for (int c = 0; c < 4; ++c) {
            mb[c] = mb[c] + (ba[c] - mb[c]) * 0.5f;
            ma[c] = ma[c] + (a[c] - ma[c]) * 0.5f;
            ms[c] = ms[c] + (ma[c] + mb[c] - ms[c]) * 0.5f;
            sp[c] = (ms[c] > 1.0f) ? (_Float16)1.0f : (_Float16)0.0f;
            ms[c] = (ms[c] > 1.0f) ? 0.0f : ms[c];
        }
        *(f16x4*)(SPh + ((size_t)(t * 2048 + r) << 9) + f) = sp;
    }
}

// ml scan over T=8; emits spmean = (1/8) sum_t sp2_t.
__global__ __launch_bounds__(256) void k_scan2(
    const float* __restrict__ H, const float* __restrict__ b1,
    float* __restrict__ spmean)
{
    const int idx = blockIdx.x * 256 + threadIdx.x;
    const int r = idx >> 7;
    const int f = (idx & 127) << 2;

    float4 b1v = *(const float4*)(b1 + f);
    float bb[4] = {b1v.x, b1v.y, b1v.z, b1v.w};
    float ml[4] = {0, 0, 0, 0}, acc[4] = {0, 0, 0, 0};
#pragma unroll
    for (int t = 0; t < 8; ++t) {
        float4 hv = *(const float4*)(H + ((size_t)(t * 2048 + r) << 9) + f);
        float h[4] = {hv.x, hv.y, hv.z, hv.w};
#pragma unroll
        for (int c = 0; c < 4; ++c) {
            float hb = h[c] + bb[c];
            ml[c] = ml[c] + (hb - ml[c]) * 0.5f;
            float s2 = (ml[c] > 0.5f) ? 1.0f : 0.0f;
            acc[c] += s2;
            ml[c] = (ml[c] > 0.5f) ? 0.0f : ml[c];
        }
    }
    *(float4*)(spmean + ((size_t)r << 9) + f) =
        make_float4(acc[0] * 0.125f, acc[1] * 0.125f, acc[2] * 0.125f, acc[3] * 0.125f);
}

// out[b,l,s] = spmean[row] . W2[l] + b2[l];  out is [64,18,32]
__global__ __launch_bounds__(64) void k_out(
    const float* __restrict__ spmean, const float* __restrict__ W2,
    const float* __restrict__ b2, float* __restrict__ out)
{
    __shared__ float row[512];
    const int r = blockIdx.x;
    const int tid = threadIdx.x;

    const float4* src = (const float4*)(spmean + ((size_t)r << 9));
    ((float4*)row)[tid]      = src[tid];
    ((float4*)row)[tid + 64] = src[tid + 64];
    __syncthreads();

    if (tid < 18) {
        const float4* w = (const float4*)(W2 + (size_t)tid * 512);
        float acc = 0.0f;
#pragma unroll 4
        for (int c = 0; c < 128; ++c) {
            float4 wv = w[c];
            float4 rv = ((const float4*)row)[c];
            acc += rv.x * wv.x + rv.y * wv.y + rv.z * wv.z + rv.w * wv.w;
        }
        acc += b2[tid];
        const int b = r >> 5, s = r & 31;
        out[((size_t)(b * 18 + tid) << 5) + s] = acc;
    }
}

extern "C" void kernel_launch(void* const* d_in, const int* in_sizes, int n_in,
                              void* d_out, int out_size, void* d_ws, size_t ws_size,
                              hipStream_t stream)
{
    const float* SE = (const float*)d_in[0];   // [8,64,3136]
    const float* TE = (const float*)d_in[1];   // [8,2048,3136]
    const float* Wb = (const float*)d_in[2];   // [512,3136]
    const float* Wa = (const float*)d_in[3];   // [512,3136]
    const float* W1 = (const float*)d_in[4];   // [512,512]
    const float* b1 = (const float*)d_in[5];   // [512]
    const float* W2 = (const float*)d_in[6];   // [18,512]
    const float* b2 = (const float*)d_in[7];   // [18]
    float* out = (float*)d_out;                // [64,18,32]

    char* ws = (char*)d_ws;
    size_t off = 0;
    float*    Abuf   = (float*)(ws + off);     off += 33554432;  // [16384,512] f32 (apical, then H)
    float*    Cb     = (float*)(ws + off);     off += 1048576;   // [512,512] f32
    float*    spmean = (float*)(ws + off);     off += 4194304;   // [2048,512] f32
    _Float16* SPh    = (_Float16*)(ws + off);  off += 16777216;  // [16384,512] f16
    _Float16* W1h    = (_Float16*)(ws + off);  off += 524288;
    _Float16* W1l    = (_Float16*)(ws + off);  off += 524288;
    _Float16* Wah    = (_Float16*)(ws + off);  off += 3211264;
    _Float16* Wal    = (_Float16*)(ws + off);  off += 3211264;
    _Float16* Wbh    = (_Float16*)(ws + off);  off += 3211264;
    _Float16* Wbl    = (_Float16*)(ws + off);  off += 3211264;
    // total ~69 MB

    // weights -> f16 hi/lo (tiny, bandwidth-trivial)
    hipLaunchKernelGGL(k_cvt, dim3(784), dim3(256), 0, stream, Wa, Wah, Wal);
    hipLaunchKernelGGL(k_cvt, dim3(784), dim3(256), 0, stream, Wb, Wbh, Wbl);
    hipLaunchKernelGGL(k_cvt, dim3(128), dim3(256), 0, stream, W1, W1h, W1l);

    hipLaunchKernelGGL(k_front, dim3(528), dim3(256), 0, stream,
                       TE, SE, Wah, Wal, Wbh, Wbl, Abuf, Cb);
    hipLaunchKernelGGL(k_scan1, dim3(1024), dim3(256), 0, stream, Abuf, Cb, SPh);
    hipLaunchKernelGGL(k_gemm3, dim3(512), dim3(256), 0, stream, SPh, W1h, W1l, Abuf);
    hipLaunchKernelGGL(k_scan2, dim3(1024), dim3(256), 0, stream, Abuf, b1, spmean);
    hipLaunchKernelGGL(k_out, dim3(2048), dim3(64), 0, stream, spmean, W2, b2, out);
}

// Round 5
// 631.528 us; speedup vs baseline: 1.0667x; 1.0667x over previous
//
#include <hip/hip_runtime.h>

typedef _Float16 f16x8 __attribute__((ext_vector_type(8)));
typedef _Float16 f16x4 __attribute__((ext_vector_type(4)));
typedef float    f32x4 __attribute__((ext_vector_type(4)));

#define SPLIT_SCALE 4096.0f
#define SPLIT_INV   (1.0f / 4096.0f)

// async global->LDS DMA, 16 bytes/lane (LDS dest = wave-uniform base + lane*16)
__device__ __forceinline__ void gld_lds16(const void* g, void* l) {
    __builtin_amdgcn_global_load_lds(
        (const __attribute__((address_space(1))) unsigned int*)g,
        (__attribute__((address_space(3))) unsigned int*)l,
        16, 0, 0);
}

// fp32 x8 -> f16 hi + f16 lo*4096
__device__ __forceinline__ void cvt8(const float4 a, const float4 b,
                                     f16x8& h, f16x8& l) {
    float v[8] = {a.x, a.y, a.z, a.w, b.x, b.y, b.z, b.w};
#pragma unroll
    for (int j = 0; j < 8; ++j) {
        _Float16 x = (_Float16)v[j];
        h[j] = x;
        l[j] = (_Float16)((v[j] - (float)x) * SPLIT_SCALE);
    }
}

// weights fp32 -> (hi, lo) f16
__global__ __launch_bounds__(256) void k_cvt(
    const float* __restrict__ src, _Float16* __restrict__ h, _Float16* __restrict__ l)
{
    const size_t i = ((size_t)blockIdx.x * 256 + threadIdx.x) * 8;
    float4 v0 = *(const float4*)(src + i);
    float4 v1 = *(const float4*)(src + i + 4);
    f16x8 hh, ll;
    cvt8(v0, v1, hh, ll);
    *(f16x8*)(h + i) = hh;
    *(f16x8*)(l + i) = ll;
}

// ---------------------------------------------------------------------------
// Front GEMM core: C[128x128] = A_f32[M,K] @ (Bh+Bl/4096)[N,K]^T, BK=64.
// Wave w computes rows w*32..w*32+31 x all 128 cols (distinct A rows/wave).
// A: direct global->register fragments (row l15, cols quad*8..+7), inline
//    hi/lo split; WAR on frag regs orders convert after MFMA consumption.
// B: LDS DMA double-buffer, XOR-swizzled 16B chunks (conflict-free ds_read).
// ---------------------------------------------------------------------------
__device__ __forceinline__ void front_core(
    const float* __restrict__ A,
    const _Float16* __restrict__ Bh_g, const _Float16* __restrict__ Bl_g,
    float* __restrict__ C, int K, int m0, int n0)
{
    __shared__ _Float16 BhL[2][128 * 64];
    __shared__ _Float16 BlL[2][128 * 64];

    const int tid  = threadIdx.x;
    const int lane = tid & 63;
    const int wave = tid >> 6;
    const int quad = lane >> 4;
    const int l15  = lane & 15;

    // --- B DMA: wave stages rows wave*32+8j+(lane>>3), swizzled 16B chunk ---
    const int srow   = wave * 32 + (lane >> 3);
    const int schunk = (((lane & 7) ^ ((lane >> 3) & 7))) * 8;   // f16 elems
    const size_t gB  = (size_t)(n0 + srow) * (size_t)K + schunk;
    const int ldsw   = (wave * 32) * 64;                          // elem offset

    // --- A direct fragment pointers: rows wave*32 + {0,16} + l15 ---
    const float* A0 = A + (size_t)(m0 + wave * 32 + l15) * (size_t)K + quad * 8;
    const float* A1 = A0 + (size_t)16 * K;

    f32x4 accm[2][8], accc[2][8];
#pragma unroll
    for (int i = 0; i < 2; ++i)
#pragma unroll
        for (int j = 0; j < 8; ++j) {
            accm[i][j] = (f32x4){0.f, 0.f, 0.f, 0.f};
            accc[i][j] = (f32x4){0.f, 0.f, 0.f, 0.f};
        }

    const int nIter = K >> 6;

    float4 ar[8];               // pending A fp32: [i*4 + kc*2 + half]
    f16x8 fah[2][2], fal[2][2]; // current A frags [i][kc]

    // ---- prologue: B tile0 DMA + A tile0 load/convert ----
#pragma unroll
    for (int j = 0; j < 4; ++j) {
        gld_lds16(Bh_g + gB + (size_t)(8 * j) * K, BhL[0] + ldsw + 8 * j * 64);
        gld_lds16(Bl_g + gB + (size_t)(8 * j) * K, BlL[0] + ldsw + 8 * j * 64);
    }
    ar[0] = *(const float4*)(A0);      ar[1] = *(const float4*)(A0 + 4);
    ar[2] = *(const float4*)(A0 + 32); ar[3] = *(const float4*)(A0 + 36);
    ar[4] = *(const float4*)(A1);      ar[5] = *(const float4*)(A1 + 4);
    ar[6] = *(const float4*)(A1 + 32); ar[7] = *(const float4*)(A1 + 36);
#pragma unroll
    for (int i = 0; i < 2; ++i)
#pragma unroll
        for (int kc = 0; kc < 2; ++kc)
            cvt8(ar[i * 4 + kc * 2], ar[i * 4 + kc * 2 + 1], fah[i][kc], fal[i][kc]);

    for (int it = 0; it < nIter; ++it) {
        __syncthreads();                 // B buf[it&1] landed
        const int cur = it & 1;
        const int nxt = cur ^ 1;
        const bool more = (it + 1) < nIter;

        if (more) {                      // prefetch tile it+1
            const size_t kb = (size_t)(it + 1) * 64;
#pragma unroll
            for (int j = 0; j < 4; ++j) {
                gld_lds16(Bh_g + gB + (size_t)(8 * j) * K + kb, BhL[nxt] + ldsw + 8 * j * 64);
                gld_lds16(Bl_g + gB + (size_t)(8 * j) * K + kb, BlL[nxt] + ldsw + 8 * j * 64);
            }
            const float* p0 = A0 + kb;
            const float* p1 = A1 + kb;
            ar[0] = *(const float4*)(p0);      ar[1] = *(const float4*)(p0 + 4);
            ar[2] = *(const float4*)(p0 + 32); ar[3] = *(const float4*)(p0 + 36);
            ar[4] = *(const float4*)(p1);      ar[5] = *(const float4*)(p1 + 4);
            ar[6] = *(const float4*)(p1 + 32); ar[7] = *(const float4*)(p1 + 36);
        }

        // ---- consume current B buffer with current A frags ----
#pragma unroll
        for (int kc = 0; kc < 2; ++kc) {
#pragma unroll
            for (int jh = 0; jh < 2; ++jh) {
                f16x8 fbh[4], fbl[4];
#pragma unroll
                for (int j = 0; j < 4; ++j) {
                    const int jj = jh * 4 + j;
                    const int p  = (((kc * 4 + quad) ^ (l15 & 7))) * 8;
                    const int e  = (jj * 16 + l15) * 64 + p;
                    fbh[j] = *(const f16x8*)&BhL[cur][e];
                    fbl[j] = *(const f16x8*)&BlL[cur][e];
                }
#pragma unroll
                for (int i = 0; i < 2; ++i)
#pragma unroll
                    for (int j = 0; j < 4; ++j) {
                        const int jj = jh * 4 + j;
                        accm[i][jj] = __builtin_amdgcn_mfma_f32_16x16x32_f16(fah[i][kc], fbh[j], accm[i][jj], 0, 0, 0);
                        accc[i][jj] = __builtin_amdgcn_mfma_f32_16x16x32_f16(fah[i][kc], fbl[j], accc[i][jj], 0, 0, 0);
                        accc[i][jj] = __builtin_amdgcn_mfma_f32_16x16x32_f16(fal[i][kc], fbh[j], accc[i][jj], 0, 0, 0);
                    }
            }
        }

        if (more) {   // convert prefetched A (WAR on fah/fal keeps this below MFMAs)
#pragma unroll
            for (int i = 0; i < 2; ++i)
#pragma unroll
                for (int kc = 0; kc < 2; ++kc)
                    cvt8(ar[i * 4 + kc * 2], ar[i * 4 + kc * 2 + 1], fah[i][kc], fal[i][kc]);
        }
    }

    // ---- epilogue: D rows quad*4+r, cols l15 ----
#pragma unroll
    for (int i = 0; i < 2; ++i)
#pragma unroll
        for (int jj = 0; jj < 8; ++jj)
#pragma unroll
            for (int r = 0; r < 4; ++r) {
                const int row = m0 + wave * 32 + i * 16 + quad * 4 + r;
                const int col = n0 + jj * 16 + l15;
                C[(size_t)row * 512 + col] = accm[i][jj][r] + accc[i][jj][r] * SPLIT_INV;
            }
}

// blocks [0,512): Apical (m-major mapping for XCD L2 A-reuse); [512,528): Basal
__global__ __launch_bounds__(256, 2) void k_front(
    const float* __restrict__ TE, const float* __restrict__ SE,
    const _Float16* __restrict__ Wah, const _Float16* __restrict__ Wal,
    const _Float16* __restrict__ Wbh, const _Float16* __restrict__ Wbl,
    float* __restrict__ Abuf, float* __restrict__ Cb)
{
    const int bid = blockIdx.x;
    if (bid < 512) {
        front_core(TE, Wah, Wal, Abuf, 3136, (bid & 127) * 128, (bid >> 7) * 128);
    } else {
        const int b = bid - 512;
        front_core(SE, Wbh, Wbl, Cb, 3136, (b & 3) * 128, (b >> 2) * 128);
    }
}

// H = SP(f16 exact) @ (W1h + W1l/4096)^T. A direct register frags (no cvt).
__global__ __launch_bounds__(256, 2) void k_gemm3(
    const _Float16* __restrict__ SPh, const _Float16* __restrict__ W1h,
    const _Float16* __restrict__ W1l, float* __restrict__ H)
{
    __shared__ _Float16 BhL[2][128 * 64];
    __shared__ _Float16 BlL[2][128 * 64];

    const int bid = blockIdx.x;
    const int m0 = (bid & 127) * 128, n0 = (bid >> 7) * 128;
    const int tid  = threadIdx.x;
    const int lane = tid & 63;
    const int wave = tid >> 6;
    const int quad = lane >> 4;
    const int l15  = lane & 15;

    const int srow   = wave * 32 + (lane >> 3);
    const int schunk = (((lane & 7) ^ ((lane >> 3) & 7))) * 8;
    const size_t gB  = (size_t)(n0 + srow) * 512 + schunk;
    const int ldsw   = (wave * 32) * 64;

    const _Float16* A0 = SPh + (size_t)(m0 + wave * 32 + l15) * 512 + quad * 8;
    const _Float16* A1 = A0 + (size_t)16 * 512;

    f32x4 accm[2][8], accl[2][8];
#pragma unroll
    for (int i = 0; i < 2; ++i)
#pragma unroll
        for (int j = 0; j < 8; ++j) {
            accm[i][j] = (f32x4){0.f, 0.f, 0.f, 0.f};
            accl[i][j] = (f32x4){0.f, 0.f, 0.f, 0.f};
        }

#pragma unroll
    for (int j = 0; j < 4; ++j) {
        gld_lds16(W1h + gB + (size_t)(8 * j) * 512, BhL[0] + ldsw + 8 * j * 64);
        gld_lds16(W1l + gB + (size_t)(8 * j) * 512, BlL[0] + ldsw + 8 * j * 64);
    }

    for (int it = 0; it < 8; ++it) {
        __syncthreads();
        const int cur = it & 1;
        const int nxt = cur ^ 1;
        if (it + 1 < 8) {
            const size_t kb = (size_t)(it + 1) * 64;
#pragma unroll
            for (int j = 0; j < 4; ++j) {
                gld_lds16(W1h + gB + (size_t)(8 * j) * 512 + kb, BhL[nxt] + ldsw + 8 * j * 64);
                gld_lds16(W1l + gB + (size_t)(8 * j) * 512 + kb, BlL[nxt] + ldsw + 8 * j * 64);
            }
        }
        // A frags: direct 16B loads in MFMA layout
        f16x8 fa[2][2];
        const size_t ka = (size_t)it * 64;
#pragma unroll
        for (int i = 0; i < 2; ++i)
#pragma unroll
            for (int kc = 0; kc < 2; ++kc)
                fa[i][kc] = *(const f16x8*)((i ? A1 : A0) + ka + kc * 32);

#pragma unroll
        for (int kc = 0; kc < 2; ++kc) {
#pragma unroll
            for (int jh = 0; jh < 2; ++jh) {
                f16x8 fbh[4], fbl[4];
#pragma unroll
                for (int j = 0; j < 4; ++j) {
                    const int jj = jh * 4 + j;
                    const int p  = (((kc * 4 + quad) ^ (l15 & 7))) * 8;
                    const int e  = (jj * 16 + l15) * 64 + p;
                    fbh[j] = *(const f16x8*)&BhL[cur][e];
                    fbl[j] = *(const f16x8*)&BlL[cur][e];
                }
#pragma unroll
                for (int i = 0; i < 2; ++i)
#pragma unroll
                    for (int j = 0; j < 4; ++j) {
                        const int jj = jh * 4 + j;
                        accm[i][jj] = __builtin_amdgcn_mfma_f32_16x16x32_f16(fa[i][kc], fbh[j], accm[i][jj], 0, 0, 0);
                        accl[i][jj] = __builtin_amdgcn_mfma_f32_16x16x32_f16(fa[i][kc], fbl[j], accl[i][jj], 0, 0, 0);
                    }
            }
        }
    }

#pragma unroll
    for (int i = 0; i < 2; ++i)
#pragma unroll
        for (int jj = 0; jj < 8; ++jj)
#pragma unroll
            for (int r = 0; r < 4; ++r) {
                const int row = m0 + wave * 32 + i * 16 + quad * 4 + r;
                const int col = n0 + jj * 16 + l15;
                H[(size_t)row * 512 + col] = accm[i][jj][r] + accl[i][jj][r] * SPLIT_INV;
            }
}

// mb/ma/ms scan over T=8; emits SP (f16, exact 0/1).
__global__ __launch_bounds__(256) void k_scan1(
    const float* __restrict__ Abuf, const float* __restrict__ Cb,
    _Float16* __restrict__ SPh)
{
    const int idx = blockIdx.x * 256 + threadIdx.x;
    const int r = idx >> 7;
    const int f = (idx & 127) << 2;
    const int b = r >> 5;

    float mb[4] = {0, 0, 0, 0}, ma[4] = {0, 0, 0, 0}, ms[4] = {0, 0, 0, 0};
#pragma unroll
    for (int t = 0; t < 8; ++t) {
        float4 av = *(const float4*)(Abuf + ((size_t)(t * 2048 + r) << 9) + f);
        float4 bv = *(const float4*)(Cb + ((size_t)(t * 64 + b) << 9) + f);
        float a[4] = {av.x, av.y, av.z, av.w};
        float ba[4] = {bv.x, bv.y, bv.z, bv.w};
        f16x4 sp;
#pragma unroll
        for (int c = 0; c < 4; ++c) {
            mb[c] = mb[c] + (ba[c] - mb[c]) * 0.5f;
            ma[c] = ma[c] + (a[c] - ma[c]) * 0.5f;
            ms[c] = ms[c] + (ma[c] + mb[c] - ms[c]) * 0.5f;
            sp[c] = (ms[c] > 1.0f) ? (_Float16)1.0f : (_Float16)0.0f;
            ms[c] = (ms[c] > 1.0f) ? 0.0f : ms[c];
        }
        *(f16x4*)(SPh + ((size_t)(t * 2048 + r) << 9) + f) = sp;
    }
}

// ml scan over T=8; emits spmean = (1/8) sum_t sp2_t.
__global__ __launch_bounds__(256) void k_scan2(
    const float* __restrict__ H, const float* __restrict__ b1,
    float* __restrict__ spmean)
{
    const int idx = blockIdx.x * 256 + threadIdx.x;
    const int r = idx >> 7;
    const int f = (idx & 127) << 2;

    float4 b1v = *(const float4*)(b1 + f);
    float bb[4] = {b1v.x, b1v.y, b1v.z, b1v.w};
    float ml[4] = {0, 0, 0, 0}, acc[4] = {0, 0, 0, 0};
#pragma unroll
    for (int t = 0; t < 8; ++t) {
        float4 hv = *(const float4*)(H + ((size_t)(t * 2048 + r) << 9) + f);
        float h[4] = {hv.x, hv.y, hv.z, hv.w};
#pragma unroll
        for (int c = 0; c < 4; ++c) {
            float hb = h[c] + bb[c];
            ml[c] = ml[c] + (hb - ml[c]) * 0.5f;
            float s2 = (ml[c] > 0.5f) ? 1.0f : 0.0f;
            acc[c] += s2;
            ml[c] = (ml[c] > 0.5f) ? 0.0f : ml[c];
        }
    }
    *(float4*)(spmean + ((size_t)r << 9) + f) =
        make_float4(acc[0] * 0.125f, acc[1] * 0.125f, acc[2] * 0.125f, acc[3] * 0.125f);
}

// out[b,l,s] = spmean[row] . W2[l] + b2[l];  out is [64,18,32]
__global__ __launch_bounds__(64) void k_out(
    const float* __restrict__ spmean, const float* __restrict__ W2,
    const float* __restrict__ b2, float* __restrict__ out)
{
    __shared__ float row[512];
    const int r = blockIdx.x;
    const int tid = threadIdx.x;

    const float4* src = (const float4*)(spmean + ((size_t)r << 9));
    ((float4*)row)[tid]      = src[tid];
    ((float4*)row)[tid + 64] = src[tid + 64];
    __syncthreads();

    if (tid < 18) {
        const float4* w = (const float4*)(W2 + (size_t)tid * 512);
        float acc = 0.0f;
#pragma unroll 4
        for (int c = 0; c < 128; ++c) {
            float4 wv = w[c];
            float4 rv = ((const float4*)row)[c];
            acc += rv.x * wv.x + rv.y * wv.y + rv.z * wv.z + rv.w * wv.w;
        }
        acc += b2[tid];
        const int b = r >> 5, s = r & 31;
        out[((size_t)(b * 18 + tid) << 5) + s] = acc;
    }
}

extern "C" void kernel_launch(void* const* d_in, const int* in_sizes, int n_in,
                              void* d_out, int out_size, void* d_ws, size_t ws_size,
                              hipStream_t stream)
{
    const float* SE = (const float*)d_in[0];   // [8,64,3136]
    const float* TE = (const float*)d_in[1];   // [8,2048,3136]
    const float* Wb = (const float*)d_in[2];   // [512,3136]
    const float* Wa = (const float*)d_in[3];   // [512,3136]
    const float* W1 = (const float*)d_in[4];   // [512,512]
    const float* b1 = (const float*)d_in[5];   // [512]
    const float* W2 = (const float*)d_in[6];   // [18,512]
    const float* b2 = (const float*)d_in[7];   // [18]
    float* out = (float*)d_out;                // [64,18,32]

    char* ws = (char*)d_ws;
    size_t off = 0;
    float*    Abuf   = (float*)(ws + off);     off += 33554432;  // [16384,512] f32 (apical, then H)
    float*    Cb     = (float*)(ws + off);     off += 1048576;   // [512,512] f32
    float*    spmean = (float*)(ws + off);     off += 4194304;   // [2048,512] f32
    _Float16* SPh    = (_Float16*)(ws + off);  off += 16777216;  // [16384,512] f16
    _Float16* W1h    = (_Float16*)(ws + off);  off += 524288;
    _Float16* W1l    = (_Float16*)(ws + off);  off += 524288;
    _Float16* Wah    = (_Float16*)(ws + off);  off += 3211264;
    _Float16* Wal    = (_Float16*)(ws + off);  off += 3211264;
    _Float16* Wbh    = (_Float16*)(ws + off);  off += 3211264;
    _Float16* Wbl    = (_Float16*)(ws + off);  off += 3211264;
    // total ~69 MB

    hipLaunchKernelGGL(k_cvt, dim3(784), dim3(256), 0, stream, Wa, Wah, Wal);
    hipLaunchKernelGGL(k_cvt, dim3(784), dim3(256), 0, stream, Wb, Wbh, Wbl);
    hipLaunchKernelGGL(k_cvt, dim3(128), dim3(256), 0, stream, W1, W1h, W1l);

    hipLaunchKernelGGL(k_front, dim3(528), dim3(256), 0, stream,
                       TE, SE, Wah, Wal, Wbh, Wbl, Abuf, Cb);
    hipLaunchKernelGGL(k_scan1, dim3(1024), dim3(256), 0, stream, Abuf, Cb, SPh);
    hipLaunchKernelGGL(k_gemm3, dim3(512), dim3(256), 0, stream, SPh, W1h, W1l, Abuf);
    hipLaunchKernelGGL(k_scan2, dim3(1024), dim3(256), 0, stream, Abuf, b1, spmean);
    hipLaunchKernelGGL(k_out, dim3(2048), dim3(64), 0, stream, spmean, W2, b2, out);
}